// Round 2
// baseline (243.604 us; speedup 1.0000x reference)
//
#include <hip/hip_runtime.h>
#include <stdint.h>

using i32x4  = __attribute__((ext_vector_type(4)))  int;
using i32x16 = __attribute__((ext_vector_type(16))) int;

#define M_TOT 8192
#define N_TOT 4096
#define K_TOT 4096
#define BM 128
#define BN 128
#define BK 64
#define KTILES (K_TOT / BK)

// async global->LDS, 16B per lane; LDS dest is wave-uniform base + lane*16
__device__ __forceinline__ void gload_lds16(const void* g, void* l) {
  __builtin_amdgcn_global_load_lds(
      (const __attribute__((address_space(1))) void*)(uintptr_t)g,
      (__attribute__((address_space(3))) void*)(uint32_t)(uintptr_t)l,
      16, 0, 0);
}

// pack int32 (low byte) -> int8 ; n16 = count of 16-element groups
__global__ void pack_i32_to_i8(const int* __restrict__ in, int8_t* __restrict__ out, int n16) {
  int stride = gridDim.x * blockDim.x;
  for (int i = blockIdx.x * blockDim.x + threadIdx.x; i < n16; i += stride) {
    const i32x4* p = (const i32x4*)in + (size_t)i * 4;
    i32x4 a = p[0], b = p[1], c = p[2], d = p[3];
    i32x4 o;
    o.x = (a.x & 255) | ((a.y & 255) << 8) | ((a.z & 255) << 16) | (a.w << 24);
    o.y = (b.x & 255) | ((b.y & 255) << 8) | ((b.z & 255) << 16) | (b.w << 24);
    o.z = (c.x & 255) | ((c.y & 255) << 8) | ((c.z & 255) << 16) | (c.w << 24);
    o.w = (d.x & 255) | ((d.y & 255) << 8) | ((d.z & 255) << 16) | (d.w << 24);
    ((i32x4*)out)[i] = o;
  }
}

// C = A(int8 MxK) * W^T(int8 NxK), epilogue clip(round(alpha*acc + beta*bias))
// -> int32 output (harness widens the reference's int8 output to int32)
__global__ __launch_bounds__(256) void gemm_w8a8(
    const int8_t* __restrict__ A,    // [M][K]
    const int8_t* __restrict__ W,    // [N][K]
    const int*    __restrict__ bias, // [N] (int32-widened int8)
    const float*  __restrict__ alphap,
    const float*  __restrict__ betap,
    int* __restrict__ out)           // [M][N] int32
{
  __shared__ __align__(16) char lds[2][2][BM * BK];  // [dbuf][A|B][8192 B]

  // bijective XCD swizzle: 2048 wgs, 8 XCDs, 256 per XCD; tn-fast within XCD
  const int bid = blockIdx.x;
  const int cpx = (M_TOT / BM) * (N_TOT / BN) / 8;   // 256
  const int wg  = (bid & 7) * cpx + (bid >> 3);
  const int tm  = wg >> 5;                           // / (N_TOT/BN = 32)
  const int tn  = wg & 31;
  const int brow = tm * BM;
  const int bcol = tn * BN;

  const int tid = threadIdx.x;
  const int w   = tid >> 6;
  const int l   = tid & 63;
  const int wr  = w >> 1;   // wave row 0..1
  const int wc  = w & 1;    // wave col 0..1

  // ---- staging: chunk c covers LDS rows [c*16, c*16+16), 64B/row, linear ----
  // lane l -> row r = c*16 + (l>>2), byte-in-row (l&3)*16.
  // LDS logical layout: byte(row,k) = row*64 + (k ^ (((row>>1)&3)<<4))
  // => pre-swizzle the GLOBAL k so linear LDS writes land swizzled (rule #21).
  const int c0 = w * 2, c1 = w * 2 + 1;
  const int r0 = c0 * 16 + (l >> 2);
  const int r1 = c1 * 16 + (l >> 2);
  const int kb0 = ((l & 3) ^ ((r0 >> 1) & 3)) << 4;
  const int kb1 = ((l & 3) ^ ((r1 >> 1) & 3)) << 4;
  const int8_t* srcA0 = A + (size_t)(brow + r0) * K_TOT + kb0;
  const int8_t* srcA1 = A + (size_t)(brow + r1) * K_TOT + kb1;
  const int8_t* srcB0 = W + (size_t)(bcol + r0) * K_TOT + kb0;
  const int8_t* srcB1 = W + (size_t)(bcol + r1) * K_TOT + kb1;

  // ---- fragment LDS byte offsets (lane-fixed) ----
  // A frag (32x32x32 i8): lane holds row = l&31, k = (l>>5)*16 + j
  const int lr = l & 31;
  const int kfrag = (l >> 5) * 16;
  int offA[2][2], offB[2][2];
#pragma unroll
  for (int mi = 0; mi < 2; ++mi) {
#pragma unroll
    for (int kk = 0; kk < 2; ++kk) {
      const int rowa = wr * 64 + mi * 32 + lr;
      const int rowb = wc * 64 + mi * 32 + lr;
      const int k    = kk * 32 + kfrag;
      offA[mi][kk] = rowa * BK + (k ^ (((rowa >> 1) & 3) << 4));
      offB[mi][kk] = rowb * BK + (k ^ (((rowb >> 1) & 3) << 4));
    }
  }

  i32x16 acc[2][2] = {};

  // prologue: stage K-tile 0 into buf 0
  gload_lds16(srcA0, &lds[0][0][c0 * 1024]);
  gload_lds16(srcA1, &lds[0][0][c1 * 1024]);
  gload_lds16(srcB0, &lds[0][1][c0 * 1024]);
  gload_lds16(srcB1, &lds[0][1][c1 * 1024]);
  asm volatile("s_waitcnt vmcnt(0)" ::: "memory");
  __syncthreads();

  int cur = 0;
  for (int kt = 0; kt < KTILES; ++kt) {
    if (kt + 1 < KTILES) {  // prefetch next K-tile into other buffer
      const int ko = (kt + 1) * BK;
      gload_lds16(srcA0 + ko, &lds[cur ^ 1][0][c0 * 1024]);
      gload_lds16(srcA1 + ko, &lds[cur ^ 1][0][c1 * 1024]);
      gload_lds16(srcB0 + ko, &lds[cur ^ 1][1][c0 * 1024]);
      gload_lds16(srcB1 + ko, &lds[cur ^ 1][1][c1 * 1024]);
    }
    const char* la = &lds[cur][0][0];
    const char* lb = &lds[cur][1][0];
#pragma unroll
    for (int kk = 0; kk < 2; ++kk) {
      i32x4 af[2], bf[2];
#pragma unroll
      for (int mi = 0; mi < 2; ++mi)
        af[mi] = *(const i32x4*)(la + offA[mi][kk]);
#pragma unroll
      for (int ni = 0; ni < 2; ++ni)
        bf[ni] = *(const i32x4*)(lb + offB[ni][kk]);
#pragma unroll
      for (int mi = 0; mi < 2; ++mi)
#pragma unroll
        for (int ni = 0; ni < 2; ++ni)
          acc[mi][ni] = __builtin_amdgcn_mfma_i32_32x32x32_i8(af[mi], bf[ni], acc[mi][ni], 0, 0, 0);
    }
    asm volatile("s_waitcnt vmcnt(0)" ::: "memory");
    __syncthreads();
    cur ^= 1;
  }

  // ---- epilogue: y = clip(rint(alpha*acc + beta*bias), -128, 127) as int32 ----
  // C/D layout (32x32, dtype-independent): col = lane&31,
  // row = (reg&3) + 8*(reg>>2) + 4*(lane>>5)
  const float alpha = *alphap;
  const float beta  = *betap;
#pragma unroll
  for (int ni = 0; ni < 2; ++ni) {
    const int col = bcol + wc * 64 + ni * 32 + lr;
    const float bb = beta * (float)bias[col];
#pragma unroll
    for (int mi = 0; mi < 2; ++mi) {
      const int rbase = brow + wr * 64 + mi * 32 + 4 * (l >> 5);
#pragma unroll
      for (int r = 0; r < 16; ++r) {
        const int row = rbase + (r & 3) + 8 * (r >> 2);
        float v = alpha * (float)acc[mi][ni][r] + bb;
        v = rintf(v);
        v = fminf(127.f, fmaxf(-128.f, v));
        out[(size_t)row * N_TOT + col] = (int)v;
      }
    }
  }
}

extern "C" void kernel_launch(void* const* d_in, const int* in_sizes, int n_in,
                              void* d_out, int out_size, void* d_ws, size_t ws_size,
                              hipStream_t stream) {
  const int*   x32    = (const int*)d_in[0];   // (4,2048,4096) int8 widened to int32
  const int*   w32    = (const int*)d_in[1];   // (4096,4096)
  const int*   bias   = (const int*)d_in[2];   // (1,4096)
  const float* alphap = (const float*)d_in[3];
  const float* betap  = (const float*)d_in[4];
  int* out = (int*)d_out;                      // int8 ref output widened to int32

  int8_t* xp = (int8_t*)d_ws;                         // 33554432 B
  int8_t* wp = xp + (size_t)M_TOT * K_TOT;            // +16777216 B (need 50331648 B total)

  pack_i32_to_i8<<<2048, 256, 0, stream>>>(x32, xp, (M_TOT * K_TOT) / 16);
  pack_i32_to_i8<<<1024, 256, 0, stream>>>(w32, wp, (N_TOT * K_TOT) / 16);

  gemm_w8a8<<<dim3((M_TOT / BM) * (N_TOT / BN)), dim3(256), 0, stream>>>(
      xp, wp, bias, alphap, betap, out);
}

// Round 3
// 207.816 us; speedup vs baseline: 1.1722x; 1.1722x over previous
//
#include <hip/hip_runtime.h>
#include <stdint.h>

using i32x4  = __attribute__((ext_vector_type(4)))  int;
using i32x16 = __attribute__((ext_vector_type(16))) int;

#define M_TOT 8192
#define N_TOT 4096
#define K_TOT 4096
#define BM 256
#define BN 256
#define BK 128
#define NT (K_TOT / BK)   // 32 K-tiles

// async global->LDS, 16B/lane; LDS dest = wave-uniform base + lane*16
__device__ __forceinline__ void gload_lds16(const void* g, void* l) {
  __builtin_amdgcn_global_load_lds(
      (const __attribute__((address_space(1))) void*)(uintptr_t)g,
      (__attribute__((address_space(3))) void*)(uint32_t)(uintptr_t)l,
      16, 0, 0);
}

// Repack int32-widened int8 [P*256][4096] into swizzled K-chunk tiles:
// chunk (p,kc) is 16KB: [rr 0..255][64B], 16B-slot sp holds logical slot
// sp ^ ((rr>>1)&3)  (bank-conflict swizzle baked into the layout so GEMM
// staging is a pure linear copy and ds_read applies the same XOR).
__global__ void pack_tiles(const int* __restrict__ in, int8_t* __restrict__ out, int ngroups) {
  int stride = gridDim.x * blockDim.x;
  for (int idx = blockIdx.x * blockDim.x + threadIdx.x; idx < ngroups; idx += stride) {
    int sp = idx & 3;
    int rr = (idx >> 2) & 255;
    int kc = (idx >> 10) & 63;
    int p  = idx >> 16;
    int sl = sp ^ ((rr >> 1) & 3);
    const i32x4* src = (const i32x4*)(in + (((size_t)(p * 256 + rr)) << 12) + kc * 64 + sl * 16);
    i32x4 a = src[0], b = src[1], c = src[2], d = src[3];
    i32x4 o;
    o.x = (a.x & 255) | ((a.y & 255) << 8) | ((a.z & 255) << 16) | (a.w << 24);
    o.y = (b.x & 255) | ((b.y & 255) << 8) | ((b.z & 255) << 16) | (b.w << 24);
    o.z = (c.x & 255) | ((c.y & 255) << 8) | ((c.z & 255) << 16) | (c.w << 24);
    o.w = (d.x & 255) | ((d.y & 255) << 8) | ((d.z & 255) << 16) | (d.w << 24);
    ((i32x4*)out)[idx] = o;
  }
}

// stage one 16KB part (kc chunk) -> LDS region; wave w copies [w*2048, w*2048+2048)
#define STAGE(srcbase, kc, ldsbuf, isB, h)                                          \
  { const int8_t* _g = (srcbase) + (size_t)(kc) * 16384 + w * 2048 + l * 16;        \
    char* _d = &lds[ldsbuf][(isB) * 32768 + (h) * 16384 + w * 2048];                \
    gload_lds16(_g, _d);                                                            \
    gload_lds16(_g + 1024, _d + 1024); }

__global__ __launch_bounds__(512, 2) void gemm_w8a8(
    const int8_t* __restrict__ Apack,  // [32 pm][64 kc][256 r][64B] swizzled
    const int8_t* __restrict__ Bpack,  // [16 pn][64 kc][256 r][64B] swizzled
    const int*    __restrict__ bias,
    const float*  __restrict__ alphap,
    const float*  __restrict__ betap,
    int* __restrict__ out)             // [M][N] int32
{
  __shared__ __align__(16) char lds[2][65536];  // [dbuf][A 32KB | B 32KB]

  // XCD swizzle: 512 wgs, 8 XCDs, 64/XCD; tm-fast -> 2 B-panels (2MB) per XCD chunk
  const int bid = blockIdx.x;
  const int wg  = (bid & 7) * 64 + (bid >> 3);
  const int tm  = wg & 31;
  const int tn  = wg >> 5;

  const int tid = threadIdx.x;
  const int w   = tid >> 6;
  const int l   = tid & 63;
  const int lr  = l & 31;
  const int hi  = l >> 5;
  const int wr  = w >> 2;   // 0..1  (wave rows)
  const int wc  = w & 3;    // 0..3  (wave cols)

  const int8_t* Asrc = Apack + (size_t)tm * (64 * 16384);
  const int8_t* Bsrc = Bpack + (size_t)tn * (64 * 16384);

  // fragment ds_read byte offsets: LDS A = [h][256 r][64B], B at +32768
  // byte = h*16384 + row*64 + ((slog)^swz)*16 ; slog = (ks&1)*2 + hi
  const int swz = (lr >> 1) & 3;
  int aRow[4], bRow[2], kOff[4];
#pragma unroll
  for (int mi = 0; mi < 4; ++mi) aRow[mi] = (wr * 128 + mi * 32 + lr) * 64;
#pragma unroll
  for (int ni = 0; ni < 2; ++ni) bRow[ni] = 32768 + (wc * 64 + ni * 32 + lr) * 64;
#pragma unroll
  for (int ks = 0; ks < 4; ++ks)
    kOff[ks] = (ks >> 1) * 16384 + (((((ks & 1) << 1) | hi)) ^ swz) * 16;

  i32x16 acc[4][2] = {};

  // prologue: stage K-tile 0 in consumption order (A-h0, B-h0, A-h1, B-h1)
  STAGE(Asrc, 0, 0, 0, 0);
  STAGE(Bsrc, 0, 0, 1, 0);
  STAGE(Asrc, 1, 0, 0, 1);
  STAGE(Bsrc, 1, 0, 1, 1);

  for (int t = 0; t < NT; ++t) {
    const int b  = t & 1;
    const int nb = b ^ 1;
    const char* L = lds[b];
    const bool more = (t + 1 < NT);
    const int kcn = 2 * (t + 1);
#pragma unroll
    for (int ks = 0; ks < 4; ++ks) {
      if ((ks & 1) == 0) {
        // counted vmcnt: the 4 oldest in-flight loads are exactly the K-half
        // consumed in the next two phases; never 0 except final drain.
        if (!more && ks == 2) { asm volatile("s_waitcnt vmcnt(0)" ::: "memory"); }
        else                  { asm volatile("s_waitcnt vmcnt(4)" ::: "memory"); }
        __builtin_amdgcn_s_barrier();
        __builtin_amdgcn_sched_barrier(0);
      }
      i32x4 af[4], bf[2];
      const int ko = kOff[ks];
#pragma unroll
      for (int mi = 0; mi < 4; ++mi) af[mi] = *(const i32x4*)(L + aRow[mi] + ko);
#pragma unroll
      for (int ni = 0; ni < 2; ++ni) bf[ni] = *(const i32x4*)(L + bRow[ni] + ko);
      if (more) {
        if (ks == 0) STAGE(Asrc, kcn,     nb, 0, 0);
        if (ks == 1) STAGE(Bsrc, kcn,     nb, 1, 0);
        if (ks == 2) STAGE(Asrc, kcn + 1, nb, 0, 1);
        if (ks == 3) STAGE(Bsrc, kcn + 1, nb, 1, 1);
      }
      asm volatile("s_waitcnt lgkmcnt(0)" ::: "memory");
      __builtin_amdgcn_sched_barrier(0);   // rule #18: pin MFMA below the wait
      __builtin_amdgcn_s_setprio(1);
#pragma unroll
      for (int mi = 0; mi < 4; ++mi)
#pragma unroll
        for (int ni = 0; ni < 2; ++ni)
          acc[mi][ni] = __builtin_amdgcn_mfma_i32_32x32x32_i8(af[mi], bf[ni], acc[mi][ni], 0, 0, 0);
      __builtin_amdgcn_s_setprio(0);
    }
  }

  // epilogue: y = clip(rint(alpha*acc + beta*bias)) -> int32
  // C/D 32x32 layout: col = lane&31, row = (reg&3) + 8*(reg>>2) + 4*(lane>>5)
  const float alpha = *alphap;
  const float beta  = *betap;
  const int brow = tm * BM, bcol = tn * BN;
#pragma unroll
  for (int ni = 0; ni < 2; ++ni) {
    const int col = bcol + wc * 64 + ni * 32 + lr;
    const float bb = beta * (float)bias[col];
#pragma unroll
    for (int mi = 0; mi < 4; ++mi) {
      const int rbase = brow + wr * 128 + mi * 32 + 4 * hi;
#pragma unroll
      for (int r = 0; r < 16; ++r) {
        const int row = rbase + (r & 3) + 8 * (r >> 2);
        float v = alpha * (float)acc[mi][ni][r] + bb;
        v = rintf(v);
        v = fminf(127.f, fmaxf(-128.f, v));
        out[(size_t)row * N_TOT + col] = (int)v;
      }
    }
  }
}

extern "C" void kernel_launch(void* const* d_in, const int* in_sizes, int n_in,
                              void* d_out, int out_size, void* d_ws, size_t ws_size,
                              hipStream_t stream) {
  const int*   x32    = (const int*)d_in[0];   // (4,2048,4096) int8 widened to int32
  const int*   w32    = (const int*)d_in[1];   // (4096,4096)
  const int*   bias   = (const int*)d_in[2];   // (1,4096)
  const float* alphap = (const float*)d_in[3];
  const float* betap  = (const float*)d_in[4];
  int* out = (int*)d_out;

  int8_t* xp = (int8_t*)d_ws;                  // Apack: 32 MB
  int8_t* wp = xp + (size_t)M_TOT * K_TOT;     // Bpack: 16 MB (48 MB ws total)

  pack_tiles<<<2048, 256, 0, stream>>>(x32, xp, (M_TOT * K_TOT) / 16);
  pack_tiles<<<1024, 256, 0, stream>>>(w32, wp, (N_TOT * K_TOT) / 16);

  gemm_w8a8<<<512, 512, 0, stream>>>(xp, wp, bias, alphap, betap, out);
}

// Round 4
// 200.641 us; speedup vs baseline: 1.2141x; 1.0358x over previous
//
#include <hip/hip_runtime.h>
#include <stdint.h>

using i32x4  = __attribute__((ext_vector_type(4)))  int;
using i32x16 = __attribute__((ext_vector_type(16))) int;

#define M_TOT 8192
#define N_TOT 4096
#define K_TOT 4096
#define BM 256
#define BN 256
// K is processed in 64-byte "halves" (chunks); half j = kc j, j = 0..63

__device__ __forceinline__ void gload_lds16(const void* g, void* l) {
  __builtin_amdgcn_global_load_lds(
      (const __attribute__((address_space(1))) void*)(uintptr_t)g,
      (__attribute__((address_space(3))) void*)(uint32_t)(uintptr_t)l,
      16, 0, 0);
}

// Repack int32-widened int8 [rows][4096] into swizzled K-chunk tiles:
// chunk (p,kc) = 16KB: [rr 0..255][64B]; physical 16B-slot sp holds logical
// slot sp ^ ((rr>>1)&3). Staging in GEMM is then a pure linear copy and the
// ds_read applies the same XOR (both-sides-or-neither, rule #21).
__global__ void pack_tiles(const int* __restrict__ a32, const int* __restrict__ b32,
                           int8_t* __restrict__ ap, int8_t* __restrict__ bp,
                           int na, int ntot) {
  int stride = gridDim.x * blockDim.x;
  for (int idx = blockIdx.x * blockDim.x + threadIdx.x; idx < ntot; idx += stride) {
    int i = idx;
    const int* src;
    int8_t* dst;
    if (idx < na) { src = a32; dst = ap; }
    else          { src = b32; dst = bp; i = idx - na; }
    int sp = i & 3;
    int rr = (i >> 2) & 255;
    int kc = (i >> 10) & 63;
    int p  = i >> 16;
    int sl = sp ^ ((rr >> 1) & 3);
    const i32x4* s = (const i32x4*)(src + (((size_t)(p * 256 + rr)) << 12) + kc * 64 + sl * 16);
    i32x4 a = s[0], b = s[1], c = s[2], d = s[3];
    i32x4 o;
    o.x = (a.x & 255) | ((a.y & 255) << 8) | ((a.z & 255) << 16) | (a.w << 24);
    o.y = (b.x & 255) | ((b.y & 255) << 8) | ((b.z & 255) << 16) | (b.w << 24);
    o.z = (c.x & 255) | ((c.y & 255) << 8) | ((c.z & 255) << 16) | (c.w << 24);
    o.w = (d.x & 255) | ((d.y & 255) << 8) | ((d.z & 255) << 16) | (d.w << 24);
    ((i32x4*)dst)[i] = o;
  }
}

// LDS ring: A halves at region r*16384, B halves at 65536 + r*16384, r = j & 3
#define STAGE_H(jj, R) {                                                   \
    const int8_t* _ga = Asrc + ((size_t)(jj) << 14) + stoff;               \
    char* _da = lds + (((R) & 3) << 14) + w * 2048;                        \
    gload_lds16(_ga, _da); gload_lds16(_ga + 1024, _da + 1024);            \
    const int8_t* _gb = Bsrc + ((size_t)(jj) << 14) + stoff;               \
    char* _db = lds + 65536 + (((R) & 3) << 14) + w * 2048;                \
    gload_lds16(_gb, _db); gload_lds16(_gb + 1024, _db + 1024); }

#define LOAD_FRAGS(DA, DB, R, S) {                                         \
    const int _so = ((((S) << 1) | hi) ^ swz) * 16;                        \
    const char* _pa = lds + (((R) & 3) << 14) + _so;                       \
    const char* _pb = _pa + 65536;                                         \
    _Pragma("unroll")                                                      \
    for (int mi = 0; mi < 4; ++mi) DA[mi] = *(const i32x4*)(_pa + aRow[mi]); \
    _Pragma("unroll")                                                      \
    for (int ni = 0; ni < 2; ++ni) DB[ni] = *(const i32x4*)(_pb + bRow[ni]); }

#define MFMA8(A, B)                                                        \
    _Pragma("unroll")                                                      \
    for (int mi = 0; mi < 4; ++mi)                                         \
    _Pragma("unroll")                                                      \
    for (int ni = 0; ni < 2; ++ni)                                         \
      acc[mi][ni] = __builtin_amdgcn_mfma_i32_32x32x32_i8(A[mi], B[ni], acc[mi][ni], 0, 0, 0);

// One half-interval j (region R0 = j&3, next R1 = (j+1)&3).
// VM is a literal string. Entry vmcnt retires stage(j+1) (one-deeper).
#define INTERVAL(j, R0, R1, VM, DO_STAGE, DO_NEXT) {                       \
    asm volatile("s_waitcnt vmcnt(" VM ")" ::: "memory");                  \
    __builtin_amdgcn_s_barrier();                                          \
    __builtin_amdgcn_sched_barrier(0);                                     \
    if (DO_STAGE) STAGE_H((j) + 3, (R0) + 3);                              \
    LOAD_FRAGS(a1, b1, R0, 1)                                              \
    __builtin_amdgcn_sched_barrier(0);                                     \
    __builtin_amdgcn_s_setprio(1);                                         \
    MFMA8(a0, b0)                                                          \
    __builtin_amdgcn_s_setprio(0);                                         \
    __builtin_amdgcn_sched_barrier(0);                                     \
    if (DO_NEXT) LOAD_FRAGS(a0, b0, R1, 0)                                 \
    __builtin_amdgcn_sched_barrier(0);                                     \
    __builtin_amdgcn_s_setprio(1);                                         \
    MFMA8(a1, b1)                                                          \
    __builtin_amdgcn_s_setprio(0); }

__global__ __launch_bounds__(512, 2) void gemm_w8a8(
    const int8_t* __restrict__ Apack,  // [32 pm][64 kc][256 r][64B] swizzled
    const int8_t* __restrict__ Bpack,  // [16 pn][64 kc][256 r][64B] swizzled
    const int*    __restrict__ bias,
    const float*  __restrict__ alphap,
    const float*  __restrict__ betap,
    int* __restrict__ out)             // [M][N] int32
{
  __shared__ __align__(16) char lds[131072];  // A ring 4x16KB | B ring 4x16KB

  // XCD-aware 8x8 chunking: xcd = bid&7; within-chunk 8 tm x 8 tn so the 32
  // concurrent wgs per XCD share ~8 A-panels + 4 B-panels (L2-friendly).
  const int bid = blockIdx.x;
  const int xcd = bid & 7, wi = bid >> 3;
  const int tm = (xcd & 3) * 8 + (wi & 7);    // 0..31
  const int tn = (xcd >> 2) * 8 + (wi >> 3);  // 0..15

  const int tid = threadIdx.x;
  const int w   = tid >> 6;
  const int l   = tid & 63;
  const int lr  = l & 31;
  const int hi  = l >> 5;
  const int wr  = w >> 2;   // 0..1
  const int wc  = w & 3;    // 0..3
  const int stoff = w * 2048 + l * 16;

  const int8_t* Asrc = Apack + (size_t)tm * (64 * 16384);
  const int8_t* Bsrc = Bpack + (size_t)tn * (64 * 16384);

  const int swz = (lr >> 1) & 3;
  int aRow[4], bRow[2];
#pragma unroll
  for (int mi = 0; mi < 4; ++mi) aRow[mi] = (wr * 128 + mi * 32 + lr) * 64;
#pragma unroll
  for (int ni = 0; ni < 2; ++ni) bRow[ni] = (wc * 64 + ni * 32 + lr) * 64;

  i32x16 acc[4][2] = {};
  i32x4 a0[4], b0[2], a1[4], b1[2];

  // prologue: 3 halves in flight, retire half 0, preload its ks0 frags
  STAGE_H(0, 0)
  STAGE_H(1, 1)
  STAGE_H(2, 2)
  asm volatile("s_waitcnt vmcnt(8)" ::: "memory");
  __builtin_amdgcn_s_barrier();
  __builtin_amdgcn_sched_barrier(0);
  LOAD_FRAGS(a0, b0, 0, 0)

  // main: intervals j = 0..59 (steady: vmcnt(4), stage j+3, prefetch j+1 ks0)
  for (int tt = 0; tt < 15; ++tt) {
    const int j0 = tt * 4;
    INTERVAL(j0 + 0, 0, 1, "4", 1, 1)
    INTERVAL(j0 + 1, 1, 2, "4", 1, 1)
    INTERVAL(j0 + 2, 2, 3, "4", 1, 1)
    INTERVAL(j0 + 3, 3, 0, "4", 1, 1)
  }
  // tail: j = 60 (stages 63), 61 (no stage), 62 (drain to 0), 63 (last)
  INTERVAL(60, 0, 1, "4", 1, 1)
  INTERVAL(61, 1, 2, "4", 0, 1)
  INTERVAL(62, 2, 3, "0", 0, 1)
  INTERVAL(63, 3, 0, "0", 0, 0)

  // epilogue: y = clip(rint(alpha*acc + beta*bias)) -> int32
  // C/D 32x32 layout: col = lane&31, row = (reg&3) + 8*(reg>>2) + 4*(lane>>5)
  const float alpha = *alphap;
  const float beta  = *betap;
  const int brow = tm * BM, bcol = tn * BN;
#pragma unroll
  for (int ni = 0; ni < 2; ++ni) {
    const int col = bcol + wc * 64 + ni * 32 + lr;
    const float bb = beta * (float)bias[col];
#pragma unroll
    for (int mi = 0; mi < 4; ++mi) {
      const int rbase = brow + wr * 128 + mi * 32 + 4 * hi;
#pragma unroll
      for (int r = 0; r < 16; ++r) {
        const int row = rbase + (r & 3) + 8 * (r >> 2);
        float v = alpha * (float)acc[mi][ni][r] + bb;
        v = rintf(v);
        v = fminf(127.f, fmaxf(-128.f, v));
        out[(size_t)row * N_TOT + col] = (int)v;
      }
    }
  }
}

extern "C" void kernel_launch(void* const* d_in, const int* in_sizes, int n_in,
                              void* d_out, int out_size, void* d_ws, size_t ws_size,
                              hipStream_t stream) {
  const int*   x32    = (const int*)d_in[0];   // (4,2048,4096) int8 widened to int32
  const int*   w32    = (const int*)d_in[1];   // (4096,4096)
  const int*   bias   = (const int*)d_in[2];   // (1,4096)
  const float* alphap = (const float*)d_in[3];
  const float* betap  = (const float*)d_in[4];
  int* out = (int*)d_out;

  int8_t* xp = (int8_t*)d_ws;                  // Apack: 32 MB
  int8_t* wp = xp + (size_t)M_TOT * K_TOT;     // Bpack: 16 MB (48 MB ws total)

  const int na   = (M_TOT * K_TOT) / 16;
  const int ntot = na + (N_TOT * K_TOT) / 16;
  pack_tiles<<<3072, 256, 0, stream>>>(x32, w32, xp, wp, na, ntot);

  gemm_w8a8<<<512, 512, 0, stream>>>(xp, wp, bias, alphap, betap, out);
}

// Round 5
// 200.449 us; speedup vs baseline: 1.2153x; 1.0010x over previous
//
#include <hip/hip_runtime.h>
#include <stdint.h>

using i32x4  = __attribute__((ext_vector_type(4)))  int;
using i32x16 = __attribute__((ext_vector_type(16))) int;

#define M_TOT 8192
#define N_TOT 4096
#define K_TOT 4096
#define BM 256
#define BN 256
// K is processed in 64-byte "halves" (chunks); half j = kc j, j = 0..63

__device__ __forceinline__ void gload_lds16(const void* g, void* l) {
  __builtin_amdgcn_global_load_lds(
      (const __attribute__((address_space(1))) void*)(uintptr_t)g,
      (__attribute__((address_space(3))) void*)(uint32_t)(uintptr_t)l,
      16, 0, 0);
}

// Repack int32-widened int8 [rows][4096] into swizzled K-chunk tiles:
// chunk (p,kc) = 16KB: [rr 0..255][64B]; physical 16B-slot sp holds logical
// slot sp ^ ((rr>>1)&3). Staging in GEMM is then a pure linear copy and the
// ds_read applies the same XOR (both-sides-or-neither, rule #21).
__global__ void pack_tiles(const int* __restrict__ a32, const int* __restrict__ b32,
                           int8_t* __restrict__ ap, int8_t* __restrict__ bp,
                           int na, int ntot) {
  int stride = gridDim.x * blockDim.x;
  for (int idx = blockIdx.x * blockDim.x + threadIdx.x; idx < ntot; idx += stride) {
    int i = idx;
    const int* src;
    int8_t* dst;
    if (idx < na) { src = a32; dst = ap; }
    else          { src = b32; dst = bp; i = idx - na; }
    int sp = i & 3;
    int rr = (i >> 2) & 255;
    int kc = (i >> 10) & 63;
    int p  = i >> 16;
    int sl = sp ^ ((rr >> 1) & 3);
    const i32x4* s = (const i32x4*)(src + (((size_t)(p * 256 + rr)) << 12) + kc * 64 + sl * 16);
    i32x4 a = s[0], b = s[1], c = s[2], d = s[3];
    i32x4 o;
    o.x = (a.x & 255) | ((a.y & 255) << 8) | ((a.z & 255) << 16) | (a.w << 24);
    o.y = (b.x & 255) | ((b.y & 255) << 8) | ((b.z & 255) << 16) | (b.w << 24);
    o.z = (c.x & 255) | ((c.y & 255) << 8) | ((c.z & 255) << 16) | (c.w << 24);
    o.w = (d.x & 255) | ((d.y & 255) << 8) | ((d.z & 255) << 16) | (d.w << 24);
    ((i32x4*)dst)[i] = o;
  }
}

// LDS ring: A halves at region r*16384, B halves at 65536 + r*16384, r = j & 3
#define STAGE_H(jj, R) {                                                   \
    const int8_t* _ga = Asrc + ((size_t)(jj) << 14) + stoff;               \
    char* _da = lds + (((R) & 3) << 14) + w * 2048;                        \
    gload_lds16(_ga, _da); gload_lds16(_ga + 1024, _da + 1024);            \
    const int8_t* _gb = Bsrc + ((size_t)(jj) << 14) + stoff;               \
    char* _db = lds + 65536 + (((R) & 3) << 14) + w * 2048;                \
    gload_lds16(_gb, _db); gload_lds16(_gb + 1024, _db + 1024); }

#define LOAD_FRAGS(DA, DB, R, S) {                                         \
    const int _so = ((((S) << 1) | hi) ^ swz) * 16;                        \
    const char* _pa = lds + (((R) & 3) << 14) + _so;                       \
    const char* _pb = _pa + 65536;                                         \
    _Pragma("unroll")                                                      \
    for (int mi = 0; mi < 4; ++mi) DA[mi] = *(const i32x4*)(_pa + aRow[mi]); \
    _Pragma("unroll")                                                      \
    for (int ni = 0; ni < 2; ++ni) DB[ni] = *(const i32x4*)(_pb + bRow[ni]); }

#define MFMA8(A, B)                                                        \
    _Pragma("unroll")                                                      \
    for (int mi = 0; mi < 4; ++mi)                                         \
    _Pragma("unroll")                                                      \
    for (int ni = 0; ni < 2; ++ni)                                         \
      acc[mi][ni] = __builtin_amdgcn_mfma_i32_32x32x32_i8(A[mi], B[ni], acc[mi][ni], 0, 0, 0);

// One half-interval j (region R0 = j&3, next R1 = (j+1)&3).
// Entry vmcnt retires stage(j+1); barrier publishes it block-wide; the single
// sched_barrier pins everything below the barrier (R1 reads must not hoist).
// NO manual lgkm waits: ds_reads are compiler-visible loads, so the waitcnt
// pass inserts exact counted lgkmcnt at first MFMA use (full drain was the
// R4 stall: ~1500 cy/interval of exposed read latency).
#define INTERVAL(j, R0, R1, VM, DO_STAGE, DO_NEXT) {                       \
    asm volatile("s_waitcnt vmcnt(" VM ")" ::: "memory");                  \
    __builtin_amdgcn_s_barrier();                                          \
    __builtin_amdgcn_sched_barrier(0);                                     \
    if (DO_STAGE) STAGE_H((j) + 3, (R0) + 3);                              \
    LOAD_FRAGS(a1, b1, R0, 1)                                              \
    __builtin_amdgcn_s_setprio(1);                                         \
    MFMA8(a0, b0)                                                          \
    __builtin_amdgcn_s_setprio(0);                                         \
    if (DO_NEXT) LOAD_FRAGS(a0, b0, R1, 0)                                 \
    __builtin_amdgcn_s_setprio(1);                                         \
    MFMA8(a1, b1)                                                          \
    __builtin_amdgcn_s_setprio(0); }

__global__ __launch_bounds__(512, 2) void gemm_w8a8(
    const int8_t* __restrict__ Apack,  // [32 pm][64 kc][256 r][64B] swizzled
    const int8_t* __restrict__ Bpack,  // [16 pn][64 kc][256 r][64B] swizzled
    const int*    __restrict__ bias,
    const float*  __restrict__ alphap,
    const float*  __restrict__ betap,
    int* __restrict__ out)             // [M][N] int32
{
  __shared__ __align__(16) char lds[131072];  // A ring 4x16KB | B ring 4x16KB

  // XCD-aware 8x8 chunking: xcd = bid&7; within-chunk 8 tm x 8 tn so the 32
  // concurrent wgs per XCD share ~8 A-panels + 4 B-panels (L2-friendly).
  const int bid = blockIdx.x;
  const int xcd = bid & 7, wi = bid >> 3;
  const int tm = (xcd & 3) * 8 + (wi & 7);    // 0..31
  const int tn = (xcd >> 2) * 8 + (wi >> 3);  // 0..15

  const int tid = threadIdx.x;
  const int w   = tid >> 6;
  const int l   = tid & 63;
  const int lr  = l & 31;
  const int hi  = l >> 5;
  const int wr  = w >> 2;   // 0..1
  const int wc  = w & 3;    // 0..3
  const int stoff = w * 2048 + l * 16;

  const int8_t* Asrc = Apack + (size_t)tm * (64 * 16384);
  const int8_t* Bsrc = Bpack + (size_t)tn * (64 * 16384);

  const int swz = (lr >> 1) & 3;
  int aRow[4], bRow[2];
#pragma unroll
  for (int mi = 0; mi < 4; ++mi) aRow[mi] = (wr * 128 + mi * 32 + lr) * 64;
#pragma unroll
  for (int ni = 0; ni < 2; ++ni) bRow[ni] = (wc * 64 + ni * 32 + lr) * 64;

  i32x16 acc[4][2] = {};
  i32x4 a0[4], b0[2], a1[4], b1[2];

  // prologue: 3 halves in flight, retire half 0, preload its ks0 frags
  STAGE_H(0, 0)
  STAGE_H(1, 1)
  STAGE_H(2, 2)
  asm volatile("s_waitcnt vmcnt(8)" ::: "memory");
  __builtin_amdgcn_s_barrier();
  __builtin_amdgcn_sched_barrier(0);
  LOAD_FRAGS(a0, b0, 0, 0)

  // main: intervals j = 0..59 (steady: vmcnt(4), stage j+3, prefetch j+1 ks0)
  for (int tt = 0; tt < 15; ++tt) {
    const int j0 = tt * 4;
    INTERVAL(j0 + 0, 0, 1, "4", 1, 1)
    INTERVAL(j0 + 1, 1, 2, "4", 1, 1)
    INTERVAL(j0 + 2, 2, 3, "4", 1, 1)
    INTERVAL(j0 + 3, 3, 0, "4", 1, 1)
  }
  // tail: j = 60 (stages 63), 61 (no stage), 62 (drain to 0), 63 (last)
  INTERVAL(60, 0, 1, "4", 1, 1)
  INTERVAL(61, 1, 2, "4", 0, 1)
  INTERVAL(62, 2, 3, "0", 0, 1)
  INTERVAL(63, 3, 0, "0", 0, 0)

  // epilogue: y = clip(rint(alpha*acc + beta*bias)) -> int32
  // C/D 32x32 layout: col = lane&31, row = (reg&3) + 8*(reg>>2) + 4*(lane>>5)
  const float alpha = *alphap;
  const float beta  = *betap;
  const int brow = tm * BM, bcol = tn * BN;
#pragma unroll
  for (int ni = 0; ni < 2; ++ni) {
    const int col = bcol + wc * 64 + ni * 32 + lr;
    const float bb = beta * (float)bias[col];
#pragma unroll
    for (int mi = 0; mi < 4; ++mi) {
      const int rbase = brow + wr * 128 + mi * 32 + 4 * hi;
#pragma unroll
      for (int r = 0; r < 16; ++r) {
        const int row = rbase + (r & 3) + 8 * (r >> 2);
        float v = alpha * (float)acc[mi][ni][r] + bb;
        v = rintf(v);
        v = fminf(127.f, fmaxf(-128.f, v));
        out[(size_t)row * N_TOT + col] = (int)v;
      }
    }
  }
}

extern "C" void kernel_launch(void* const* d_in, const int* in_sizes, int n_in,
                              void* d_out, int out_size, void* d_ws, size_t ws_size,
                              hipStream_t stream) {
  const int*   x32    = (const int*)d_in[0];   // (4,2048,4096) int8 widened to int32
  const int*   w32    = (const int*)d_in[1];   // (4096,4096)
  const int*   bias   = (const int*)d_in[2];   // (1,4096)
  const float* alphap = (const float*)d_in[3];
  const float* betap  = (const float*)d_in[4];
  int* out = (int*)d_out;

  int8_t* xp = (int8_t*)d_ws;                  // Apack: 32 MB
  int8_t* wp = xp + (size_t)M_TOT * K_TOT;     // Bpack: 16 MB (48 MB ws total)

  const int na   = (M_TOT * K_TOT) / 16;
  const int ntot = na + (N_TOT * K_TOT) / 16;
  pack_tiles<<<3072, 256, 0, stream>>>(x32, w32, xp, wp, na, ntot);

  gemm_w8a8<<<512, 512, 0, stream>>>(xp, wp, bias, alphap, betap, out);
}

// Round 6
// 196.166 us; speedup vs baseline: 1.2418x; 1.0218x over previous
//
#include <hip/hip_runtime.h>
#include <stdint.h>

using i32x4  = __attribute__((ext_vector_type(4)))  int;
using i32x16 = __attribute__((ext_vector_type(16))) int;

#define M_TOT 8192
#define N_TOT 4096
#define K_TOT 4096
#define BM 256
#define BN 256
// K is processed in 64-byte "halves" (chunks); half j = kc j, j = 0..63

__device__ __forceinline__ void gload_lds16(const void* g, void* l) {
  __builtin_amdgcn_global_load_lds(
      (const __attribute__((address_space(1))) void*)(uintptr_t)g,
      (__attribute__((address_space(3))) void*)(uint32_t)(uintptr_t)l,
      16, 0, 0);
}

// Repack int32-widened int8 [rows][4096] into swizzled K-chunk tiles:
// chunk (p,kc) = 16KB: [rr 0..255][64B]; physical 16B-slot sp holds logical
// slot sp ^ ((rr>>1)&3). Staging in GEMM is then a pure linear copy and the
// ds_read applies the same XOR (both-sides-or-neither, rule #21).
__global__ void pack_tiles(const int* __restrict__ a32, const int* __restrict__ b32,
                           int8_t* __restrict__ ap, int8_t* __restrict__ bp,
                           int na, int ntot) {
  int stride = gridDim.x * blockDim.x;
  for (int idx = blockIdx.x * blockDim.x + threadIdx.x; idx < ntot; idx += stride) {
    int i = idx;
    const int* src;
    int8_t* dst;
    if (idx < na) { src = a32; dst = ap; }
    else          { src = b32; dst = bp; i = idx - na; }
    int sp = i & 3;
    int rr = (i >> 2) & 255;
    int kc = (i >> 10) & 63;
    int p  = i >> 16;
    int sl = sp ^ ((rr >> 1) & 3);
    const i32x4* s = (const i32x4*)(src + (((size_t)(p * 256 + rr)) << 12) + kc * 64 + sl * 16);
    i32x4 a = s[0], b = s[1], c = s[2], d = s[3];
    i32x4 o;
    o.x = (a.x & 255) | ((a.y & 255) << 8) | ((a.z & 255) << 16) | (a.w << 24);
    o.y = (b.x & 255) | ((b.y & 255) << 8) | ((b.z & 255) << 16) | (b.w << 24);
    o.z = (c.x & 255) | ((c.y & 255) << 8) | ((c.z & 255) << 16) | (c.w << 24);
    o.w = (d.x & 255) | ((d.y & 255) << 8) | ((d.z & 255) << 16) | (d.w << 24);
    ((i32x4*)dst)[i] = o;
  }
}

// LDS ring: A halves at region r*16384, B halves at 65536 + r*16384, r = j & 3
#define STAGE_H(jj, R) {                                                   \
    const int8_t* _ga = Asrc + ((size_t)(jj) << 14) + stoff;               \
    char* _da = lds + (((R) & 3) << 14) + w * 2048;                        \
    gload_lds16(_ga, _da); gload_lds16(_ga + 1024, _da + 1024);            \
    const int8_t* _gb = Bsrc + ((size_t)(jj) << 14) + stoff;               \
    char* _db = lds + 65536 + (((R) & 3) << 14) + w * 2048;                \
    gload_lds16(_gb, _db); gload_lds16(_gb + 1024, _db + 1024); }

#define LOAD_FRAGS(DA, DB, R, S) {                                         \
    const int _so = ((((S) << 1) | hi) ^ swz) * 16;                        \
    const char* _pa = lds + (((R) & 3) << 14) + _so;                       \
    const char* _pb = _pa + 65536;                                         \
    _Pragma("unroll")                                                      \
    for (int mi = 0; mi < 4; ++mi) DA[mi] = *(const i32x4*)(_pa + aRow[mi]); \
    _Pragma("unroll")                                                      \
    for (int ni = 0; ni < 2; ++ni) DB[ni] = *(const i32x4*)(_pb + bRow[ni]); }

#define MFMA8(A, B)                                                        \
    _Pragma("unroll")                                                      \
    for (int mi = 0; mi < 4; ++mi)                                         \
    _Pragma("unroll")                                                      \
    for (int ni = 0; ni < 2; ++ni)                                         \
      acc[mi][ni] = __builtin_amdgcn_mfma_i32_32x32x32_i8(A[mi], B[ni], acc[mi][ni], 0, 0, 0);

#define SGB(m, n) __builtin_amdgcn_sched_group_barrier((m), (n), 0)
// one {MFMA, DS_READ} interleave pair
#define PAIR SGB(0x8, 1); SGB(0x100, 1);

// One half-interval j (region R0 = j&3, next R1 = (j+1)&3).
// Entry vmcnt retires stage(j+1); barrier publishes; body is ONE scheduling
// region (setprio brackets the whole body) with a sched_group_barrier
// interleave: 2 VMEM, 6x{MFMA,DS}, 2 MFMA, 2 VMEM, 6x{MFMA,DS}, 2 MFMA.
// This forces the wave's in-order issue stream to alternate matrix-pipe and
// LDS-pipe ops (R5 post-mortem: un-interleaved bursts serialized the two
// pipes, 2662 cy/interval vs the ~1800 cy overlapped floor).
#define INTERVAL(j, R0, R1, VM, DO_STAGE, DO_NEXT) {                       \
    asm volatile("s_waitcnt vmcnt(" VM ")" ::: "memory");                  \
    __builtin_amdgcn_s_barrier();                                          \
    __builtin_amdgcn_sched_barrier(0);                                     \
    __builtin_amdgcn_s_setprio(1);                                         \
    if (DO_STAGE) STAGE_H((j) + 3, (R0) + 3);                              \
    LOAD_FRAGS(a1, b1, R0, 1)                                              \
    MFMA8(a0, b0)                                                          \
    if (DO_NEXT) LOAD_FRAGS(a0, b0, R1, 0)                                 \
    MFMA8(a1, b1)                                                          \
    SGB(0x10, 2);                                                          \
    PAIR PAIR PAIR PAIR PAIR PAIR                                          \
    SGB(0x8, 2);                                                           \
    SGB(0x10, 2);                                                          \
    PAIR PAIR PAIR PAIR PAIR PAIR                                          \
    SGB(0x8, 2);                                                           \
    __builtin_amdgcn_s_setprio(0); }

__global__ __launch_bounds__(512, 2) void gemm_w8a8(
    const int8_t* __restrict__ Apack,  // [32 pm][64 kc][256 r][64B] swizzled
    const int8_t* __restrict__ Bpack,  // [16 pn][64 kc][256 r][64B] swizzled
    const int*    __restrict__ bias,
    const float*  __restrict__ alphap,
    const float*  __restrict__ betap,
    int* __restrict__ out)             // [M][N] int32
{
  __shared__ __align__(16) char lds[131072];  // A ring 4x16KB | B ring 4x16KB

  // XCD-aware 8x8 chunking: xcd = bid&7; within-chunk 8 tm x 8 tn so the 32
  // concurrent wgs per XCD share ~8 A-panels + 4 B-panels (L2-friendly).
  const int bid = blockIdx.x;
  const int xcd = bid & 7, wi = bid >> 3;
  const int tm = (xcd & 3) * 8 + (wi & 7);    // 0..31
  const int tn = (xcd >> 2) * 8 + (wi >> 3);  // 0..15

  const int tid = threadIdx.x;
  const int w   = tid >> 6;
  const int l   = tid & 63;
  const int lr  = l & 31;
  const int hi  = l >> 5;
  const int wr  = w >> 2;   // 0..1
  const int wc  = w & 3;    // 0..3
  const int stoff = w * 2048 + l * 16;

  const int8_t* Asrc = Apack + (size_t)tm * (64 * 16384);
  const int8_t* Bsrc = Bpack + (size_t)tn * (64 * 16384);

  const int swz = (lr >> 1) & 3;
  int aRow[4], bRow[2];
#pragma unroll
  for (int mi = 0; mi < 4; ++mi) aRow[mi] = (wr * 128 + mi * 32 + lr) * 64;
#pragma unroll
  for (int ni = 0; ni < 2; ++ni) bRow[ni] = (wc * 64 + ni * 32 + lr) * 64;

  i32x16 acc[4][2] = {};
  i32x4 a0[4], b0[2], a1[4], b1[2];

  // prologue: 3 halves in flight, retire half 0, preload its ks0 frags
  STAGE_H(0, 0)
  STAGE_H(1, 1)
  STAGE_H(2, 2)
  asm volatile("s_waitcnt vmcnt(8)" ::: "memory");
  __builtin_amdgcn_s_barrier();
  __builtin_amdgcn_sched_barrier(0);
  LOAD_FRAGS(a0, b0, 0, 0)

  // main: intervals j = 0..59 (steady: vmcnt(4), stage j+3, prefetch j+1 ks0)
  for (int tt = 0; tt < 15; ++tt) {
    const int j0 = tt * 4;
    INTERVAL(j0 + 0, 0, 1, "4", 1, 1)
    INTERVAL(j0 + 1, 1, 2, "4", 1, 1)
    INTERVAL(j0 + 2, 2, 3, "4", 1, 1)
    INTERVAL(j0 + 3, 3, 0, "4", 1, 1)
  }
  // tail: j = 60 (stages 63), 61 (no stage), 62 (drain to 0), 63 (last)
  INTERVAL(60, 0, 1, "4", 1, 1)
  INTERVAL(61, 1, 2, "4", 0, 1)
  INTERVAL(62, 2, 3, "0", 0, 1)
  INTERVAL(63, 3, 0, "0", 0, 0)

  // epilogue: y = clip(rint(alpha*acc + beta*bias)) -> int32
  // C/D 32x32 layout: col = lane&31, row = (reg&3) + 8*(reg>>2) + 4*(lane>>5)
  const float alpha = *alphap;
  const float beta  = *betap;
  const int brow = tm * BM, bcol = tn * BN;
#pragma unroll
  for (int ni = 0; ni < 2; ++ni) {
    const int col = bcol + wc * 64 + ni * 32 + lr;
    const float bb = beta * (float)bias[col];
#pragma unroll
    for (int mi = 0; mi < 4; ++mi) {
      const int rbase = brow + wr * 128 + mi * 32 + 4 * hi;
#pragma unroll
      for (int r = 0; r < 16; ++r) {
        const int row = rbase + (r & 3) + 8 * (r >> 2);
        float v = alpha * (float)acc[mi][ni][r] + bb;
        v = rintf(v);
        v = fminf(127.f, fmaxf(-128.f, v));
        out[(size_t)row * N_TOT + col] = (int)v;
      }
    }
  }
}

extern "C" void kernel_launch(void* const* d_in, const int* in_sizes, int n_in,
                              void* d_out, int out_size, void* d_ws, size_t ws_size,
                              hipStream_t stream) {
  const int*   x32    = (const int*)d_in[0];   // (4,2048,4096) int8 widened to int32
  const int*   w32    = (const int*)d_in[1];   // (4096,4096)
  const int*   bias   = (const int*)d_in[2];   // (1,4096)
  const float* alphap = (const float*)d_in[3];
  const float* betap  = (const float*)d_in[4];
  int* out = (int*)d_out;

  int8_t* xp = (int8_t*)d_ws;                  // Apack: 32 MB
  int8_t* wp = xp + (size_t)M_TOT * K_TOT;     // Bpack: 16 MB (48 MB ws total)

  const int na   = (M_TOT * K_TOT) / 16;
  const int ntot = na + (N_TOT * K_TOT) / 16;
  pack_tiles<<<3072, 256, 0, stream>>>(x32, w32, xp, wp, na, ntot);

  gemm_w8a8<<<512, 512, 0, stream>>>(xp, wp, bias, alphap, betap, out);
}

// Round 7
// 190.475 us; speedup vs baseline: 1.2789x; 1.0299x over previous
//
#include <hip/hip_runtime.h>
#include <stdint.h>

using i32x4  = __attribute__((ext_vector_type(4)))  int;
using i32x16 = __attribute__((ext_vector_type(16))) int;

#define M_TOT 8192
#define N_TOT 4096
#define K_TOT 4096
#define BM 256
#define BN 256
#define NTILES 32   // K processed in 32 tiles of BK=128 bytes

__device__ __forceinline__ void gload_lds16(const void* g, void* l) {
  __builtin_amdgcn_global_load_lds(
      (const __attribute__((address_space(1))) void*)(uintptr_t)g,
      (__attribute__((address_space(3))) void*)(uint32_t)(uintptr_t)l,
      16, 0, 0);
}

// Repack int32-widened int8 [rows][4096] into 128B-row swizzled K-tiles:
// chunk (p,kt) = 32KB: [rr 0..255][128B]; physical 16B-slot sp holds logical
// slot sp ^ (rr&7).  128B rows => row index drops out of the bank equation
// ((r*128/4)%32 == 0), and the 3-bit XOR spreads a wave's b128 frag read
// uniformly over all 32 banks (8 lanes per 16B slot) — the conflict-free
// HK st_16x32 geometry (m201).  Staging in GEMM stays a pure linear copy.
__global__ void pack_tiles(const int* __restrict__ a32, const int* __restrict__ b32,
                           int8_t* __restrict__ ap, int8_t* __restrict__ bp,
                           int na, int ntot) {
  int stride = gridDim.x * blockDim.x;
  for (int idx = blockIdx.x * blockDim.x + threadIdx.x; idx < ntot; idx += stride) {
    int i = idx;
    const int* src;
    int8_t* dst;
    if (idx < na) { src = a32; dst = ap; }
    else          { src = b32; dst = bp; i = idx - na; }
    int sp = i & 7;             // physical 16B slot in 128B row
    int rr = (i >> 3) & 255;    // row within chunk
    int kt = (i >> 11) & 31;    // K-tile
    int p  = i >> 16;           // 256-row panel
    int sl = sp ^ (rr & 7);     // logical slot held at sp
    const i32x4* s = (const i32x4*)(src + ((size_t)(p * 256 + rr)) * 4096 + (kt * 8 + sl) * 16);
    i32x4 a = s[0], b = s[1], c = s[2], d = s[3];
    i32x4 o;
    o.x = (a.x & 255) | ((a.y & 255) << 8) | ((a.z & 255) << 16) | (a.w << 24);
    o.y = (b.x & 255) | ((b.y & 255) << 8) | ((b.z & 255) << 16) | (b.w << 24);
    o.z = (c.x & 255) | ((c.y & 255) << 8) | ((c.z & 255) << 16) | (c.w << 24);
    o.w = (d.x & 255) | ((d.y & 255) << 8) | ((d.z & 255) << 16) | (d.w << 24);
    ((i32x4*)dst)[idx < na ? i : i] = o;
    ((i32x4*)dst)[i] = o;
  }
}

// stage full 32KB A-tile + 32KB B-tile kt into buffer BUF; wave w copies
// rows [w*32, w*32+32) of each (4KB = 4 gloads per tensor per wave)
#define STAGE_T(kt, BUF) {                                                  \
    const int8_t* _ga = Asrc + ((size_t)(kt) << 15) + stoff;                \
    char* _da = lds + ((BUF) << 15) + stoff;                                \
    gload_lds16(_ga, _da);               gload_lds16(_ga + 1024, _da + 1024); \
    gload_lds16(_ga + 2048, _da + 2048); gload_lds16(_ga + 3072, _da + 3072); \
    const int8_t* _gb = Bsrc + ((size_t)(kt) << 15) + stoff;                \
    char* _db = lds + 65536 + ((BUF) << 15) + stoff;                        \
    gload_lds16(_gb, _db);               gload_lds16(_gb + 1024, _db + 1024); \
    gload_lds16(_gb + 2048, _db + 2048); gload_lds16(_gb + 3072, _db + 3072); }

// frag read for K-step S (0..3) from buffer BUF: A rows wr*128+mi*32+lr,
// B rows wc*64+ni*32+lr; slot = ((S<<1)|hi) ^ (lr&7)  (rows ≡ lr mod 8)
#define LOAD_FRAGS(DA, DB, BUF, S) {                                        \
    const int _so = ((((S) << 1) | hi) ^ sx) * 16;                          \
    const char* _pa = lds + ((BUF) << 15) + _so;                            \
    const char* _pb = _pa + 65536;                                          \
    _Pragma("unroll")                                                       \
    for (int mi = 0; mi < 4; ++mi) DA[mi] = *(const i32x4*)(_pa + aRow[mi]); \
    _Pragma("unroll")                                                       \
    for (int ni = 0; ni < 2; ++ni) DB[ni] = *(const i32x4*)(_pb + bRow[ni]); }

#define MFMA8(A, B)                                                         \
    _Pragma("unroll")                                                       \
    for (int mi = 0; mi < 4; ++mi)                                          \
    _Pragma("unroll")                                                       \
    for (int ni = 0; ni < 2; ++ni)                                          \
      acc[mi][ni] = __builtin_amdgcn_mfma_i32_32x32x32_i8(A[mi], B[ni], acc[mi][ni], 0, 0, 0);

#define SGB(m, n) __builtin_amdgcn_sched_group_barrier((m), (n), 0)
#define PAIR SGB(0x8, 1); SGB(0x100, 1);
#define KSBLOCK PAIR PAIR PAIR PAIR PAIR PAIR SGB(0x8, 2);

// One BK=128 interval: entry vmcnt(0) retires stage(kt) (issued a full
// interval ago — ~4700cy cover vs ~900cy HBM); barrier publishes; then
// issue stage(kt+1) into the idle buffer and run 4 K-steps with register
// ping-pong.  SGB forces VMEM-first then {MFMA,DS} interleave.
#define INTERVAL(kt, BUF, DO_STAGE) {                                       \
    asm volatile("s_waitcnt vmcnt(0)" ::: "memory");                        \
    __builtin_amdgcn_s_barrier();                                           \
    __builtin_amdgcn_sched_barrier(0);                                      \
    __builtin_amdgcn_s_setprio(1);                                          \
    if (DO_STAGE) STAGE_T((kt) + 1, (BUF) ^ 1);                             \
    LOAD_FRAGS(a0, b0, BUF, 0)                                              \
    LOAD_FRAGS(a1, b1, BUF, 1)                                              \
    MFMA8(a0, b0)                                                           \
    LOAD_FRAGS(a0, b0, BUF, 2)                                              \
    MFMA8(a1, b1)                                                           \
    LOAD_FRAGS(a1, b1, BUF, 3)                                              \
    MFMA8(a0, b0)                                                           \
    MFMA8(a1, b1)                                                           \
    SGB(0x10, 8);                                                           \
    SGB(0x100, 6);                                                          \
    KSBLOCK KSBLOCK KSBLOCK                                                 \
    SGB(0x8, 8);                                                            \
    __builtin_amdgcn_s_setprio(0); }

__global__ __launch_bounds__(512, 2) void gemm_w8a8(
    const int8_t* __restrict__ Apack,  // [32 pm][32 kt][256 r][128B] swizzled
    const int8_t* __restrict__ Bpack,  // [16 pn][32 kt][256 r][128B] swizzled
    const int*    __restrict__ bias,
    const float*  __restrict__ alphap,
    const float*  __restrict__ betap,
    int* __restrict__ out)             // [M][N] int32
{
  __shared__ __align__(16) char lds[131072];  // A: [2][32KB] @0 | B: [2][32KB] @64KB

  // XCD-aware 8x8 chunking (FETCH 270->98MB in R4): 32 wgs/XCD share panels
  const int bid = blockIdx.x;
  const int xcd = bid & 7, wi = bid >> 3;
  const int tm = (xcd & 3) * 8 + (wi & 7);    // 0..31
  const int tn = (xcd >> 2) * 8 + (wi >> 3);  // 0..15

  const int tid = threadIdx.x;
  const int w   = tid >> 6;
  const int l   = tid & 63;
  const int lr  = l & 31;
  const int hi  = l >> 5;
  const int wr  = w >> 2;   // 0..1
  const int wc  = w & 3;    // 0..3
  const int stoff = w * 4096 + l * 16;
  const int sx  = lr & 7;

  const int8_t* Asrc = Apack + ((size_t)tm << 20);  // 32 chunks * 32KB = 1MB
  const int8_t* Bsrc = Bpack + ((size_t)tn << 20);

  int aRow[4], bRow[2];
#pragma unroll
  for (int mi = 0; mi < 4; ++mi) aRow[mi] = (wr * 128 + mi * 32 + lr) * 128;
#pragma unroll
  for (int ni = 0; ni < 2; ++ni) bRow[ni] = (wc * 64 + ni * 32 + lr) * 128;

  i32x16 acc[4][2] = {};
  i32x4 a0[4], b0[2], a1[4], b1[2];

  // prologue: stage tile 0 into buffer 0
  STAGE_T(0, 0)

  // 32 intervals; stage kt+1 while computing kt (ring-2, full-interval cover)
  for (int tt = 0; tt < 15; ++tt) {
    const int k0 = tt * 2;
    INTERVAL(k0 + 0, 0, 1)
    INTERVAL(k0 + 1, 1, 1)
  }
  INTERVAL(30, 0, 1)
  INTERVAL(31, 1, 0)

  // epilogue: y = clip(rint(alpha*acc + beta*bias)) -> int32
  // C/D 32x32 layout: col = lane&31, row = (reg&3) + 8*(reg>>2) + 4*(lane>>5)
  const float alpha = *alphap;
  const float beta  = *betap;
  const int brow = tm * BM, bcol = tn * BN;
#pragma unroll
  for (int ni = 0; ni < 2; ++ni) {
    const int col = bcol + wc * 64 + ni * 32 + lr;
    const float bb = beta * (float)bias[col];
#pragma unroll
    for (int mi = 0; mi < 4; ++mi) {
      const int rbase = brow + wr * 128 + mi * 32 + 4 * hi;
#pragma unroll
      for (int r = 0; r < 16; ++r) {
        const int row = rbase + (r & 3) + 8 * (r >> 2);
        float v = alpha * (float)acc[mi][ni][r] + bb;
        v = rintf(v);
        v = fminf(127.f, fmaxf(-128.f, v));
        out[(size_t)row * N_TOT + col] = (int)v;
      }
    }
  }
}

extern "C" void kernel_launch(void* const* d_in, const int* in_sizes, int n_in,
                              void* d_out, int out_size, void* d_ws, size_t ws_size,
                              hipStream_t stream) {
  const int*   x32    = (const int*)d_in[0];   // (4,2048,4096) int8 widened to int32
  const int*   w32    = (const int*)d_in[1];   // (4096,4096)
  const int*   bias   = (const int*)d_in[2];   // (1,4096)
  const float* alphap = (const float*)d_in[3];
  const float* betap  = (const float*)d_in[4];
  int* out = (int*)d_out;

  int8_t* xp = (int8_t*)d_ws;                  // Apack: 32 MB
  int8_t* wp = xp + (size_t)M_TOT * K_TOT;     // Bpack: 16 MB (48 MB ws total)

  const int na   = (M_TOT * K_TOT) / 16;
  const int ntot = na + (N_TOT * K_TOT) / 16;
  pack_tiles<<<3072, 256, 0, stream>>>(x32, w32, xp, wp, na, ntot);

  gemm_w8a8<<<512, 512, 0, stream>>>(xp, wp, bias, alphap, betap, out);
}